// Round 11
// baseline (158.428 us; speedup 1.0000x reference)
//
#include <hip/hip_runtime.h>

#define BB 8
#define SS 4096
#define DD 768
#define NN 64
#define D4 (DD / 4)        // 192 float4 columns
#define CHT 128            // tokens per chunk
#define MAXCH 96           // max chunks per batch: 64 + 4032/128 = 95 <= 96
#define NREC (BB * MAXCH)  // 768 chunk records
#define WAVES 8
#define BLOCK (WAVES * 64)
// ws layout: float sum[NREC][DD] (2,359,296 B) then u8 cnt[NREC][DD] (589,824 B)
// total 2,949,120 B <= ws_size. No zero-init: every record read by finalize
// is written by exactly one owner block.

// native vector type accepted by __builtin_nontemporal_load
typedef float nfloat4 __attribute__((ext_vector_type(4)));

// ---------------- Phase B: full-row chunk partials, NO atomics --------------
// grid: (MAXCH, BB), block 512 (8 waves). Block (cidx,b) owns one chunk
// (<=128 tokens, wholly inside one segment). Wave w takes tokens t0+w
// stride 8 and reads the ENTIRE 3 KiB token row contiguously (3 nt 1 KiB
// loads) -> each DRAM page is opened once and fully consumed, unlike the
// colgroup-split variant (1 KiB granules at 3 KiB stride from 3 different
// blocks). LDS tree-reduce across waves; plain stores to a unique record.
__global__ __launch_bounds__(BLOCK) void chunk_kernel(
    const float* __restrict__ wv,
    const int* __restrict__ lens,
    float* __restrict__ ws_sum,
    unsigned char* __restrict__ ws_cnt)
{
    const int cidx = blockIdx.x;     // chunk slot within batch
    const int b    = blockIdx.y;
    const int tid  = threadIdx.x;
    const int lane = tid & 63;
    const int w    = tid >> 6;       // 0..7

    // per-wave redundant scans over the 64 segment lengths
    const int l    = lens[b * NN + lane];
    const int nchl = (l + CHT - 1) >> 7;      // chunks in this segment
    int inclen = l, inch = nchl;
    #pragma unroll
    for (int off = 1; off < 64; off <<= 1) {
        int a = __shfl_up(inclen, off); if (lane >= off) inclen += a;
        int c = __shfl_up(inch,   off); if (lane >= off) inch   += c;
    }
    const int total_ch = __shfl(inch, 63);
    if (cidx >= total_ch) return;             // uniform: whole block exits

    // owning segment: first n with inclusive chunk-scan > cidx
    unsigned long long m = __ballot(inch > cidx);
    const int n         = __ffsll(m) - 1;
    const int seg_len   = __shfl(l, n);
    const int seg_start = __shfl(inclen, n) - seg_len;
    const int ch_base   = __shfl(inch, n) - __shfl(nchl, n);
    const int t0 = seg_start + (cidx - ch_base) * CHT;
    const int t1 = min(seg_start + seg_len, t0 + CHT);

    const nfloat4* base = (const nfloat4*)wv + (size_t)b * SS * D4;

    float4 s0 = make_float4(0,0,0,0), s1 = s0, s2 = s0;
    float4 c0 = s0, c1 = s0, c2 = s0;
    #pragma unroll 2
    for (int t = t0 + w; t < t1; t += WAVES) {
        const nfloat4* row = base + (size_t)t * D4 + lane;
        nfloat4 v0 = __builtin_nontemporal_load(row);
        nfloat4 v1 = __builtin_nontemporal_load(row + 64);
        nfloat4 v2 = __builtin_nontemporal_load(row + 128);
        s0.x += v0.x; s0.y += v0.y; s0.z += v0.z; s0.w += v0.w;
        s1.x += v1.x; s1.y += v1.y; s1.z += v1.z; s1.w += v1.w;
        s2.x += v2.x; s2.y += v2.y; s2.z += v2.z; s2.w += v2.w;
        c0.x += (v0.x != 0.f) ? 1.f : 0.f; c0.y += (v0.y != 0.f) ? 1.f : 0.f;
        c0.z += (v0.z != 0.f) ? 1.f : 0.f; c0.w += (v0.w != 0.f) ? 1.f : 0.f;
        c1.x += (v1.x != 0.f) ? 1.f : 0.f; c1.y += (v1.y != 0.f) ? 1.f : 0.f;
        c1.z += (v1.z != 0.f) ? 1.f : 0.f; c1.w += (v1.w != 0.f) ? 1.f : 0.f;
        c2.x += (v2.x != 0.f) ? 1.f : 0.f; c2.y += (v2.y != 0.f) ? 1.f : 0.f;
        c2.z += (v2.z != 0.f) ? 1.f : 0.f; c2.w += (v2.w != 0.f) ? 1.f : 0.f;
    }

    __shared__ float4 s_s[WAVES][D4];   // 24 KB
    __shared__ float4 s_c[WAVES][D4];   // 24 KB
    s_s[w][lane]       = s0;
    s_s[w][64 + lane]  = s1;
    s_s[w][128 + lane] = s2;
    s_c[w][lane]       = c0;
    s_c[w][64 + lane]  = c1;
    s_c[w][128 + lane] = c2;
    __syncthreads();

    if (tid < D4) {
        float4 S = make_float4(0,0,0,0);
        float4 C = make_float4(0,0,0,0);
        #pragma unroll
        for (int j = 0; j < WAVES; ++j) {
            float4 a = s_s[j][tid], d = s_c[j][tid];
            S.x += a.x; S.y += a.y; S.z += a.z; S.w += a.w;
            C.x += d.x; C.y += d.y; C.z += d.z; C.w += d.w;
        }
        const size_t rec = (size_t)(b * MAXCH + cidx);
        ((float4*)ws_sum)[rec * D4 + tid] = S;
        uchar4 u;                      // chunk counts <= 128, exact in u8
        u.x = (unsigned char)C.x; u.y = (unsigned char)C.y;
        u.z = (unsigned char)C.z; u.w = (unsigned char)C.w;
        ((uchar4*)ws_cnt)[rec * D4 + tid] = u;
    }
}

// ---------------- Phase C: finalize (mean, fallback, rep, masks) -----------
// grid: BB*NN = 512 blocks, 256 threads (192 active cols). Gathers the
// segment's K chunk records, then proven epilogue. (Unchanged from R8/R10.)
__global__ __launch_bounds__(256) void finalize_kernel(
    const float* __restrict__ wv,
    const int* __restrict__ rep_ids,
    const float* __restrict__ rep_mask,
    const int* __restrict__ lens,
    const float* __restrict__ len_mask,
    const float* __restrict__ ws_sum,
    const unsigned char* __restrict__ ws_cnt,
    float* __restrict__ out)
{
    __shared__ float s_part[4];
    __shared__ int s_info[2];
    const int sgid = blockIdx.x;          // b*NN + n
    const int b = sgid >> 6, n = sgid & 63;
    const int tid = threadIdx.x;
    const int lane = tid & 63;

    if (tid < 64) {                       // wave 0: chunk-base scan
        const int l    = lens[b * NN + tid];
        const int nchl = (l + CHT - 1) >> 7;
        int inch = nchl;
        #pragma unroll
        for (int off = 1; off < 64; off <<= 1) {
            int a = __shfl_up(inch, off); if (lane >= off) inch += a;
        }
        if (tid == n) { s_info[0] = inch - nchl; s_info[1] = nchl; }
    }
    __syncthreads();
    const int ch_base = s_info[0];
    const int K       = s_info[1];
    const bool active = tid < D4;

    float4 S = make_float4(0,0,0,0), C = S;
    if (active) {
        for (int k = 0; k < K; ++k) {
            const size_t rec = (size_t)(b * MAXCH + ch_base + k);
            float4 sv = ((const float4*)ws_sum)[rec * D4 + tid];
            uchar4 cv = ((const uchar4*)ws_cnt)[rec * D4 + tid];
            S.x += sv.x; S.y += sv.y; S.z += sv.z; S.w += sv.w;
            C.x += (float)cv.x; C.y += (float)cv.y;
            C.z += (float)cv.z; C.w += (float)cv.w;
        }
    }

    float tot = C.x + C.y + C.z + C.w;    // 0 for inactive lanes
    #pragma unroll
    for (int off = 32; off; off >>= 1) tot += __shfl_xor(tot, off);
    if ((tid & 63) == 0) s_part[tid >> 6] = tot;
    __syncthreads();
    const float total = s_part[0] + s_part[1] + s_part[2] + s_part[3];

    if (active) {
        float4 mean;
        mean.x = S.x / fmaxf(C.x, 1.f);
        mean.y = S.y / fmaxf(C.y, 1.f);
        mean.z = S.z / fmaxf(C.z, 1.f);
        mean.w = S.w / fmaxf(C.w, 1.f);
        if (total == 0.f) mean = ((const float4*)wv)[tid];   // wv[0,0,:]

        const float lm = len_mask[sgid];
        mean.x *= lm; mean.y *= lm; mean.z *= lm; mean.w *= lm;

        float4* out4 = (float4*)out;
        out4[(size_t)(b * 2 * NN + NN + n) * D4 + tid] = mean;

        const int   rid = rep_ids[sgid];
        const float rm  = rep_mask[sgid];
        float4 rv = ((const float4*)wv)[(size_t)(b * SS + rid) * D4 + tid];
        rv.x *= rm; rv.y *= rm; rv.z *= rm; rv.w *= rm;
        out4[(size_t)(b * 2 * NN + n) * D4 + tid] = rv;

        if (tid == 0) {
            float* masks = out + (size_t)BB * 2 * NN * DD;
            masks[b * 2 * NN + n]      = rm;
            masks[b * 2 * NN + NN + n] = lm;
        }
    }
}

extern "C" void kernel_launch(void* const* d_in, const int* in_sizes, int n_in,
                              void* d_out, int out_size, void* d_ws, size_t ws_size,
                              hipStream_t stream) {
    const float* wv       = (const float*)d_in[0];
    const int*   rep_ids  = (const int*)d_in[1];
    const float* rep_mask = (const float*)d_in[2];
    const int*   lens     = (const int*)d_in[3];
    const float* len_mask = (const float*)d_in[4];
    float*       out      = (float*)d_out;
    float*         ws_sum = (float*)d_ws;
    unsigned char* ws_cnt = (unsigned char*)d_ws + (size_t)NREC * DD * 4;

    dim3 gridB(MAXCH, BB);
    chunk_kernel<<<gridB, BLOCK, 0, stream>>>(wv, lens, ws_sum, ws_cnt);
    finalize_kernel<<<BB * NN, 256, 0, stream>>>(wv, rep_ids, rep_mask, lens,
                                                 len_mask, ws_sum, ws_cnt, out);
}